// Round 1
// baseline (1051.269 us; speedup 1.0000x reference)
//
#include <hip/hip_runtime.h>
#include <math.h>

// ---------------------------------------------------------------------------
// Graph structure (compile-time): 6x6 grid, 120 directed edges, enumeration
// order must match the Python reference exactly:
//   for i in 0..5: for j in 0..5: for (dx,dy) in [(-1,0),(0,-1),(0,1),(1,0)]:
//       if in-range: edge (src=j*6+i, dst=(j+dy)*6+(i+dx))
// ---------------------------------------------------------------------------
struct AdjT {
    int src[120];
    int dst[120];
    int cnt[36];
    int idx[36][4];   // incoming edge lists per node (dst(e)==n)
};

constexpr AdjT build_adj() {
    AdjT a{};
    const int ddx[4] = {-1, 0, 0, 1};
    const int ddy[4] = {0, -1, 1, 0};
    int ne = 0;
    for (int i = 0; i < 6; i++)
        for (int j = 0; j < 6; j++)
            for (int d = 0; d < 4; d++) {
                int x = i + ddx[d], y = j + ddy[d];
                if (x >= 0 && x < 6 && y >= 0 && y < 6) {
                    a.src[ne] = j * 6 + i;
                    a.dst[ne] = y * 6 + x;
                    ne++;
                }
            }
    for (int n = 0; n < 36; n++) {
        a.cnt[n] = 0;
        for (int e = 0; e < 120; e++)
            if (a.dst[e] == n) a.idx[n][a.cnt[n]++] = e;
    }
    return a;
}

__device__ constexpr AdjT ADJC = build_adj();

// ---------------------------------------------------------------------------
// K1: conv1  [B,1,32,32] -> [B,32,28,28]   (VALID 5x5, bias, no activation)
// block = one image, 256 threads. Image (4KB) + weights (3.2KB) in LDS.
// ---------------------------------------------------------------------------
__global__ __launch_bounds__(256) void k_conv1(const float* __restrict__ img,
                                               const float* __restrict__ w,
                                               const float* __restrict__ bias,
                                               float* __restrict__ out) {
    __shared__ float s_img[1024];
    __shared__ float s_w[800];
    __shared__ float s_b[32];
    const int b = blockIdx.x, tid = threadIdx.x;
    const float* ip = img + (size_t)b * 1024;
    for (int t = tid; t < 1024; t += 256) s_img[t] = ip[t];
    for (int t = tid; t < 800; t += 256) s_w[t] = w[t];
    if (tid < 32) s_b[tid] = bias[tid];
    __syncthreads();
    float* op = out + (size_t)b * 25088;
    for (int idx = tid; idx < 25088; idx += 256) {
        int c = idx / 784;
        int p = idx - c * 784;
        int y = p / 28;
        int x = p - y * 28;
        float acc = s_b[c];
        const float* wr = s_w + c * 25;
#pragma unroll
        for (int ky = 0; ky < 5; ky++)
#pragma unroll
            for (int kx = 0; kx < 5; kx++)
                acc += s_img[(y + ky) * 32 + x + kx] * wr[ky * 5 + kx];
        op[idx] = acc;
    }
}

// ---------------------------------------------------------------------------
// K2: conv2 + maxpool2  [B,32,28,28] -> conv [B,32,24,24] -> pool [B,32,12,12]
// Dominant kernel (15.1 G MACs). block = half image (grid B*2), 256 threads.
// Full 32-co weight set staged in LDS in two 16-ci stages; row stride padded
// to 401 floats (odd) so per-co strides hit distinct banks.
// Register blocking: 4 output channels x 2x2 conv outputs per pooled output.
// ---------------------------------------------------------------------------
__global__ __launch_bounds__(256) void k_conv2(const float* __restrict__ in,
                                               const float* __restrict__ w,
                                               const float* __restrict__ bias,
                                               float* __restrict__ out) {
    __shared__ float s_w[32 * 401];  // [co][ci_local*25+k], padded
    const int blk = blockIdx.x;
    const int b = blk >> 1, half = blk & 1;
    const int tid = threadIdx.x;
    const float* ip = in + (size_t)b * 25088;  // [32][28][28]
    float* op = out + (size_t)b * 4608;        // [32][12][12]

    for (int chunk = 0; chunk < 3; chunk++) {
        int item = chunk * 256 + tid;
        bool active = item < 576;  // 8 cgroups * 72 pooled positions
        int cg = item / 72;
        int pos = item - cg * 72;
        int pr = pos / 12;
        int px = pos - pr * 12;
        int PR = half * 6 + pr;  // global pooled row 0..11
        float acc[4][2][2] = {};
        for (int stage = 0; stage < 2; stage++) {
            __syncthreads();
            // stage weights for ci in [stage*16, stage*16+16)
            for (int t = tid; t < 12800; t += 256) {
                int co = t / 400;
                int r = t - co * 400;
                s_w[co * 401 + r] = w[co * 800 + stage * 400 + r];
            }
            __syncthreads();
            if (active) {
                for (int ci = 0; ci < 16; ci++) {
                    int cig = stage * 16 + ci;
                    const float* base = ip + cig * 784 + (2 * PR) * 28 + 2 * px;
                    float win[6][6];
#pragma unroll
                    for (int r = 0; r < 6; r++) {
                        const float2* rp = (const float2*)(base + r * 28);
                        float2 v0 = rp[0], v1 = rp[1], v2 = rp[2];
                        win[r][0] = v0.x; win[r][1] = v0.y; win[r][2] = v1.x;
                        win[r][3] = v1.y; win[r][4] = v2.x; win[r][5] = v2.y;
                    }
#pragma unroll
                    for (int c4 = 0; c4 < 4; c4++) {
                        const float* wr = s_w + (cg * 4 + c4) * 401 + ci * 25;
#pragma unroll
                        for (int ky = 0; ky < 5; ky++)
#pragma unroll
                            for (int kx = 0; kx < 5; kx++) {
                                float wv = wr[ky * 5 + kx];
                                acc[c4][0][0] += win[ky][kx] * wv;
                                acc[c4][0][1] += win[ky][kx + 1] * wv;
                                acc[c4][1][0] += win[ky + 1][kx] * wv;
                                acc[c4][1][1] += win[ky + 1][kx + 1] * wv;
                            }
                    }
                }
            }
        }
        if (active) {
#pragma unroll
            for (int c4 = 0; c4 < 4; c4++) {
                int co = cg * 4 + c4;
                float m = fmaxf(fmaxf(acc[c4][0][0], acc[c4][0][1]),
                                fmaxf(acc[c4][1][0], acc[c4][1][1])) +
                          bias[co];
                op[co * 144 + PR * 12 + px] = m;
            }
        }
    }
}

// ---------------------------------------------------------------------------
// K3: conv3  [B,32,12,12] -> [B,64,8,8]
// block = one image, 256 threads; input tile (18KB) in LDS; weights via L2.
// item = tid: 16 cgroups(4ch) x 16 posblocks(2x2).
// ---------------------------------------------------------------------------
__global__ __launch_bounds__(256) void k_conv3(const float* __restrict__ in,
                                               const float* __restrict__ w,
                                               const float* __restrict__ bias,
                                               float* __restrict__ out) {
    __shared__ float s_in[4608];  // [32][12][12]
    const int b = blockIdx.x, tid = threadIdx.x;
    const float* ip = in + (size_t)b * 4608;
    for (int t = tid; t < 4608; t += 256) s_in[t] = ip[t];
    __syncthreads();
    const int cg = tid >> 4, pb = tid & 15;
    const int py = (pb >> 2) * 2, px = (pb & 3) * 2;
    float acc[4][2][2] = {};
    for (int ci = 0; ci < 32; ci++) {
        float win[6][6];
#pragma unroll
        for (int r = 0; r < 6; r++) {
            const float2* rp = (const float2*)(s_in + ci * 144 + (py + r) * 12 + px);
            float2 v0 = rp[0], v1 = rp[1], v2 = rp[2];
            win[r][0] = v0.x; win[r][1] = v0.y; win[r][2] = v1.x;
            win[r][3] = v1.y; win[r][4] = v2.x; win[r][5] = v2.y;
        }
#pragma unroll
        for (int c4 = 0; c4 < 4; c4++) {
            const float* wr = w + ((cg * 4 + c4) * 32 + ci) * 25;
#pragma unroll
            for (int ky = 0; ky < 5; ky++)
#pragma unroll
                for (int kx = 0; kx < 5; kx++) {
                    float wv = wr[ky * 5 + kx];
                    acc[c4][0][0] += win[ky][kx] * wv;
                    acc[c4][0][1] += win[ky][kx + 1] * wv;
                    acc[c4][1][0] += win[ky + 1][kx] * wv;
                    acc[c4][1][1] += win[ky + 1][kx + 1] * wv;
                }
        }
    }
    float* op = out + (size_t)b * 4096;
#pragma unroll
    for (int c4 = 0; c4 < 4; c4++) {
        int co = cg * 4 + c4;
        float bb = bias[co];
#pragma unroll
        for (int dy = 0; dy < 2; dy++)
#pragma unroll
            for (int dx = 0; dx < 2; dx++)
                op[co * 64 + (py + dy) * 8 + px + dx] = acc[c4][dy][dx] + bb;
    }
}

// ---------------------------------------------------------------------------
// K4: conv4 + maxpool2 + flatten  [B,64,8,8] -> [B,64,4,4] -> [B,64,2,2] -> emb [B,256]
// block = one image, 64 threads; input tile (16KB) in LDS.
// item = tid: 16 cgroups(4ch) x 4 pooled positions. Flatten = c*4 + h*2 + w.
// ---------------------------------------------------------------------------
__global__ __launch_bounds__(64) void k_conv4(const float* __restrict__ in,
                                              const float* __restrict__ w,
                                              const float* __restrict__ bias,
                                              float* __restrict__ out_emb) {
    __shared__ float s_in[4096];  // [64][8][8]
    const int b = blockIdx.x, tid = threadIdx.x;
    const float* ip = in + (size_t)b * 4096;
    for (int t = tid; t < 4096; t += 64) s_in[t] = ip[t];
    __syncthreads();
    const int cg = tid >> 2, pp = tid & 3;
    const int ppy = pp >> 1, ppx = pp & 1;
    const int y0 = ppy * 2, x0 = ppx * 2;  // conv-output block origin
    float acc[4][2][2] = {};
    for (int ci = 0; ci < 64; ci++) {
        float win[6][6];
#pragma unroll
        for (int r = 0; r < 6; r++) {
            const float2* rp = (const float2*)(s_in + ci * 64 + (y0 + r) * 8 + x0);
            float2 v0 = rp[0], v1 = rp[1], v2 = rp[2];
            win[r][0] = v0.x; win[r][1] = v0.y; win[r][2] = v1.x;
            win[r][3] = v1.y; win[r][4] = v2.x; win[r][5] = v2.y;
        }
#pragma unroll
        for (int c4 = 0; c4 < 4; c4++) {
            const float* wr = w + ((cg * 4 + c4) * 64 + ci) * 25;
#pragma unroll
            for (int ky = 0; ky < 5; ky++)
#pragma unroll
                for (int kx = 0; kx < 5; kx++) {
                    float wv = wr[ky * 5 + kx];
                    acc[c4][0][0] += win[ky][kx] * wv;
                    acc[c4][0][1] += win[ky][kx + 1] * wv;
                    acc[c4][1][0] += win[ky + 1][kx] * wv;
                    acc[c4][1][1] += win[ky + 1][kx + 1] * wv;
                }
        }
    }
#pragma unroll
    for (int c4 = 0; c4 < 4; c4++) {
        int co = cg * 4 + c4;
        float m = fmaxf(fmaxf(acc[c4][0][0], acc[c4][0][1]),
                        fmaxf(acc[c4][1][0], acc[c4][1][1])) +
                  bias[co];
        out_emb[(size_t)b * 256 + co * 4 + ppy * 2 + ppx] = m;
    }
}

// ---------------------------------------------------------------------------
// K5: heads (two 256->256->{120,36} MLPs, relu+sigmoid) + 36-iteration DAMP
// path recurrence + endpoint gating. block = one batch row, 256 threads.
// ---------------------------------------------------------------------------
__global__ __launch_bounds__(256) void k_heads_path(
    const float* __restrict__ emb,
    const float* __restrict__ ep_w1, const float* __restrict__ ep_b1,
    const float* __restrict__ ep_w2, const float* __restrict__ ep_b2,
    const float* __restrict__ cn_w1, const float* __restrict__ cn_b1,
    const float* __restrict__ cn_w2, const float* __restrict__ cn_b2,
    float* __restrict__ out) {
    __shared__ float s_emb[256];
    __shared__ float s_hid[256];
    __shared__ float s_conn[120];
    __shared__ float s_old[120];
    __shared__ float s_rec[120];
    __shared__ float s_s[36];
    __shared__ float s_ep[36];
    const int b = blockIdx.x, tid = threadIdx.x;
    s_emb[tid] = emb[(size_t)b * 256 + tid];
    __syncthreads();

    // conn hidden: relu(emb @ cn_w1.T + cn_b1)
    {
        float h = cn_b1[tid];
        const float4* wr = (const float4*)(cn_w1 + (size_t)tid * 256);
        const float4* er = (const float4*)s_emb;
        for (int k = 0; k < 64; k++) {
            float4 wv = wr[k], ev = er[k];
            h += wv.x * ev.x + wv.y * ev.y + wv.z * ev.z + wv.w * ev.w;
        }
        s_hid[tid] = fmaxf(h, 0.f);
    }
    __syncthreads();

    // conn = sigmoid(hid @ cn_w2.T + cn_b2)
    if (tid < 120) {
        float a = cn_b2[tid];
        const float4* wr = (const float4*)(cn_w2 + (size_t)tid * 256);
        const float4* hr = (const float4*)s_hid;
        for (int k = 0; k < 64; k++) {
            float4 wv = wr[k], hv = hr[k];
            a += wv.x * hv.x + wv.y * hv.y + wv.z * hv.z + wv.w * hv.w;
        }
        float c = 1.f / (1.f + __expf(-a));
        s_conn[tid] = c;
        s_old[tid] = c;
        s_rec[tid] = c;
    }

    // ep hidden (reads only s_emb; written to s_hid after conn dot consumers)
    float h2 = ep_b1[tid];
    {
        const float4* wr = (const float4*)(ep_w1 + (size_t)tid * 256);
        const float4* er = (const float4*)s_emb;
        for (int k = 0; k < 64; k++) {
            float4 wv = wr[k], ev = er[k];
            h2 += wv.x * ev.x + wv.y * ev.y + wv.z * ev.z + wv.w * ev.w;
        }
    }
    __syncthreads();
    s_hid[tid] = fmaxf(h2, 0.f);
    __syncthreads();

    // ep = sigmoid(hid @ ep_w2.T + ep_b2)
    if (tid < 36) {
        float a = ep_b2[tid];
        const float4* wr = (const float4*)(ep_w2 + (size_t)tid * 256);
        const float4* hr = (const float4*)s_hid;
        for (int k = 0; k < 64; k++) {
            float4 wv = wr[k], hv = hr[k];
            a += wv.x * hv.x + wv.y * hv.y + wv.z * hv.z + wv.w * hv.w;
        }
        s_ep[tid] = 1.f / (1.f + __expf(-a));
    }
    __syncthreads();

    // DAMP recurrence: 36 iterations
    // s[n] = sum of recent over incoming edges; new[e]=min(s[src[e]],1)*conn[e];
    // old = min(old+new, 1); recent = new.  (all values nonnegative)
    for (int it = 0; it < 36; it++) {
        if (tid < 36) {
            float sum = 0.f;
            int n = ADJC.cnt[tid];
#pragma unroll
            for (int q = 0; q < 4; q++)
                sum += (q < n) ? s_rec[ADJC.idx[tid][q]] : 0.f;
            s_s[tid] = sum;
        }
        __syncthreads();
        if (tid < 120) {
            float nv = fminf(s_s[ADJC.src[tid]], 1.f) * s_conn[tid];
            s_old[tid] = fminf(s_old[tid] + nv, 1.f);
            s_rec[tid] = nv;
        }
        __syncthreads();
    }

    if (tid == 0) out[b] = s_old[0] * s_ep[0] * s_ep[ADJC.dst[0]];
}

// ---------------------------------------------------------------------------
extern "C" void kernel_launch(void* const* d_in, const int* in_sizes, int n_in,
                              void* d_out, int out_size, void* d_ws, size_t ws_size,
                              hipStream_t stream) {
    const float* image = (const float*)d_in[0];
    const float* c1w = (const float*)d_in[1];
    const float* c1b = (const float*)d_in[2];
    const float* c2w = (const float*)d_in[3];
    const float* c2b = (const float*)d_in[4];
    const float* c3w = (const float*)d_in[5];
    const float* c3b = (const float*)d_in[6];
    const float* c4w = (const float*)d_in[7];
    const float* c4b = (const float*)d_in[8];
    const float* epw1 = (const float*)d_in[9];
    const float* epb1 = (const float*)d_in[10];
    const float* epw2 = (const float*)d_in[11];
    const float* epb2 = (const float*)d_in[12];
    const float* cnw1 = (const float*)d_in[13];
    const float* cnb1 = (const float*)d_in[14];
    const float* cnw2 = (const float*)d_in[15];
    const float* cnb2 = (const float*)d_in[16];

    const int B = in_sizes[0] / (32 * 32);  // 1024

    float* ws = (float*)d_ws;
    float* conv1o = ws;                           // B * 25088  (102.8 MB)
    float* pool2o = conv1o + (size_t)B * 25088;   // B * 4608   (18.9 MB)
    float* conv3o = pool2o + (size_t)B * 4608;    // B * 4096   (16.8 MB)
    float* embo = conv3o + (size_t)B * 4096;      // B * 256    (1.05 MB)

    k_conv1<<<B, 256, 0, stream>>>(image, c1w, c1b, conv1o);
    k_conv2<<<B * 2, 256, 0, stream>>>(conv1o, c2w, c2b, pool2o);
    k_conv3<<<B, 256, 0, stream>>>(pool2o, c3w, c3b, conv3o);
    k_conv4<<<B, 64, 0, stream>>>(conv3o, c4w, c4b, embo);
    k_heads_path<<<B, 256, 0, stream>>>(embo, epw1, epb1, epw2, epb2,
                                        cnw1, cnb1, cnw2, cnb2, (float*)d_out);
}

// Round 2
// 455.938 us; speedup vs baseline: 2.3057x; 2.3057x over previous
//
#include <hip/hip_runtime.h>
#include <math.h>

typedef __attribute__((ext_vector_type(8))) short short8;
typedef __attribute__((ext_vector_type(4))) float float4v;

static __device__ __forceinline__ unsigned short f2bf(float f) {
    union { float f; unsigned u; } v; v.f = f;
    unsigned u = v.u;
    return (unsigned short)((u + 0x7fffu + ((u >> 16) & 1u)) >> 16);
}
static __device__ __forceinline__ float bf2f(unsigned short h) {
    union { unsigned u; float f; } v; v.u = ((unsigned)h) << 16;
    return v.f;
}

// ---------------------------------------------------------------------------
// Graph structure (compile-time): 6x6 grid, 120 directed edges, matching the
// Python enumeration order exactly.
// ---------------------------------------------------------------------------
struct AdjT {
    int src[120];
    int dst[120];
    int cnt[36];
    int idx[36][4];
};

constexpr AdjT build_adj() {
    AdjT a{};
    const int ddx[4] = {-1, 0, 0, 1};
    const int ddy[4] = {0, -1, 1, 0};
    int ne = 0;
    for (int i = 0; i < 6; i++)
        for (int j = 0; j < 6; j++)
            for (int d = 0; d < 4; d++) {
                int x = i + ddx[d], y = j + ddy[d];
                if (x >= 0 && x < 6 && y >= 0 && y < 6) {
                    a.src[ne] = j * 6 + i;
                    a.dst[ne] = y * 6 + x;
                    ne++;
                }
            }
    for (int n = 0; n < 36; n++) {
        a.cnt[n] = 0;
        for (int e = 0; e < 120; e++)
            if (a.dst[e] == n) a.idx[n][a.cnt[n]++] = e;
    }
    return a;
}

__device__ constexpr AdjT ADJC = build_adj();

// ---------------------------------------------------------------------------
// K0: weight prep for conv2 MFMA. Builds B-fragments in bf16:
// wprep[t][ct][lane][j] = w2[co=ct*16+(lane&15)][ci=(lane>>4)*8+j][tap t]
// 25600 elements.
// ---------------------------------------------------------------------------
__global__ __launch_bounds__(256) void k_prep(const float* __restrict__ w,
                                              unsigned short* __restrict__ wprep) {
    int e = blockIdx.x * 256 + threadIdx.x;  // grid 100 -> exactly 25600
    int j = e & 7;
    int lane = (e >> 3) & 63;
    int ct = (e >> 9) & 1;
    int t = e >> 10;
    int n = lane & 15, q = lane >> 4;
    int co = ct * 16 + n;
    int ci = q * 8 + j;
    wprep[e] = f2bf(w[co * 800 + ci * 25 + t]);
}

// ---------------------------------------------------------------------------
// K1: conv1 [B,1,32,32] -> channel-last bf16 [B, 28*28 pos, 32 ci]
// ---------------------------------------------------------------------------
__global__ __launch_bounds__(256) void k_conv1(const float* __restrict__ img,
                                               const float* __restrict__ w,
                                               const float* __restrict__ bias,
                                               unsigned short* __restrict__ out) {
    __shared__ float s_img[1024];
    __shared__ float s_w[800];
    __shared__ float s_b[32];
    const int b = blockIdx.x, tid = threadIdx.x;
    const float* ip = img + (size_t)b * 1024;
    for (int t = tid; t < 1024; t += 256) s_img[t] = ip[t];
    for (int t = tid; t < 800; t += 256) s_w[t] = w[t];
    if (tid < 32) s_b[tid] = bias[tid];
    __syncthreads();
    unsigned short* op = out + (size_t)b * 25088;
    for (int idx = tid; idx < 25088; idx += 256) {
        int c = idx & 31;
        int pos = idx >> 5;
        int y = pos / 28;
        int x = pos - y * 28;
        float acc = s_b[c];
        const float* wr = s_w + c * 25;
#pragma unroll
        for (int ky = 0; ky < 5; ky++)
#pragma unroll
            for (int kx = 0; kx < 5; kx++)
                acc += s_img[(y + ky) * 32 + x + kx] * wr[ky * 5 + kx];
        op[idx] = f2bf(acc);
    }
}

// ---------------------------------------------------------------------------
// K2: conv2 + maxpool2 via MFMA tap-GEMM.
// Input: channel-last bf16 [B][28*28][32]. Output: pool2o fp32 [B][32][12][12].
// Block = half image, 128 threads (2 waves). Per tap (ky,kx):
//   D[pos,co] += A[pos, ci] * Wt[ci, co]  with one 16x16x32 bf16 MFMA per
//   (16-pos M-tile, 16-co N-tile). 25 taps * 9 Mtiles * 2 Ntiles per wave.
// Fragment layouts (m89/m91/m120-verified):
//   A: lane holds A[m=lane&15][k=(lane>>4)*8+j]   (16B contiguous -> b128)
//   B: lane holds B[k=(lane>>4)*8+j][n=lane&15]   (pre-swizzled in wprep)
//   D: col=lane&15 (co), row=(lane>>4)*4+reg (pos)
// ---------------------------------------------------------------------------
__global__ __launch_bounds__(128) void k_conv2(const unsigned short* __restrict__ in,
                                               const unsigned short* __restrict__ wprep,
                                               const float* __restrict__ bias,
                                               float* __restrict__ out) {
    __shared__ unsigned short s_in[448 * 32];    // 16 input rows, ch-last (28 KB)
    __shared__ unsigned short s_stage[288 * 32]; // conv out bf16, 12 rows x 24 x 32co (18 KB)
    const int blk = blockIdx.x;
    const int b = blk >> 1, half = blk & 1;
    const int tid = threadIdx.x;
    const int lane = tid & 63, wave = tid >> 6;
    const int m = lane & 15, quad = lane >> 4;

    // stage 16 input rows (rows half*12 .. half*12+15), identical layout
    {
        const short8* g8 = (const short8*)(in + (size_t)b * 25088 + half * 12 * 28 * 32);
        short8* s8 = (short8*)s_in;
        for (int i = tid; i < 1792; i += 128) s8[i] = g8[i];
    }

    // per-lane A-frag base offsets (ushort units) for tap (0,0), 9 M-tiles
    int a_idx[9];
#pragma unroll
    for (int mt = 0; mt < 9; mt++) {
        int p = wave * 144 + mt * 16 + m;  // local conv-out position, 0..287
        int yl = p / 24;
        int x = p - yl * 24;
        a_idx[mt] = (yl * 28 + x) * 32 + quad * 8;
    }

    float4v acc[9][2];
#pragma unroll
    for (int mt = 0; mt < 9; mt++) {
        acc[mt][0] = (float4v){0.f, 0.f, 0.f, 0.f};
        acc[mt][1] = (float4v){0.f, 0.f, 0.f, 0.f};
    }

    const short8* wp = (const short8*)wprep;  // [25][2][64] frags
    short8 bw0 = wp[lane];
    short8 bw1 = wp[64 + lane];

    __syncthreads();

    for (int t = 0; t < 25; t++) {
        short8 nb0, nb1;
        if (t < 24) {
            nb0 = wp[(t + 1) * 128 + lane];
            nb1 = wp[(t + 1) * 128 + 64 + lane];
        }
        const int ky = t / 5, kx = t - ky * 5;
        const int toff = (ky * 28 + kx) * 32;  // ushort units
#pragma unroll
        for (int mt = 0; mt < 9; mt++) {
            short8 av = *(const short8*)(s_in + a_idx[mt] + toff);
            acc[mt][0] = __builtin_amdgcn_mfma_f32_16x16x32_bf16(av, bw0, acc[mt][0], 0, 0, 0);
            acc[mt][1] = __builtin_amdgcn_mfma_f32_16x16x32_bf16(av, bw1, acc[mt][1], 0, 0, 0);
        }
        if (t < 24) { bw0 = nb0; bw1 = nb1; }
    }

    // write conv outputs to stage (bf16): row = quad*4+reg, col = co
    const int n = lane & 15;
#pragma unroll
    for (int mt = 0; mt < 9; mt++) {
        int pbase = wave * 144 + mt * 16 + quad * 4;
#pragma unroll
        for (int r = 0; r < 4; r++) {
            s_stage[(pbase + r) * 32 + n] = f2bf(acc[mt][0][r]);
            s_stage[(pbase + r) * 32 + 16 + n] = f2bf(acc[mt][1][r]);
        }
    }
    __syncthreads();

    // pool 2x2 + bias, write [32co][12][12] fp32 (channel-first for conv3)
    float* op = out + (size_t)b * 4608;
    for (int i = tid; i < 2304; i += 128) {
        int co = i & 31;
        int pos = i >> 5;           // 0..71 : 6 pool rows x 12 px
        int prl = pos / 12;
        int px = pos - prl * 12;
        int base = ((prl * 2) * 24 + px * 2) * 32 + co;
        float v0 = bf2f(s_stage[base]);
        float v1 = bf2f(s_stage[base + 32]);
        float v2 = bf2f(s_stage[base + 24 * 32]);
        float v3 = bf2f(s_stage[base + 25 * 32]);
        float mx = fmaxf(fmaxf(v0, v1), fmaxf(v2, v3));
        op[co * 144 + (half * 6 + prl) * 12 + px] = mx + bias[co];
    }
}

// ---------------------------------------------------------------------------
// K3: conv3  [B,32,12,12] -> [B,64,8,8]  (fp32, unchanged)
// ---------------------------------------------------------------------------
__global__ __launch_bounds__(256) void k_conv3(const float* __restrict__ in,
                                               const float* __restrict__ w,
                                               const float* __restrict__ bias,
                                               float* __restrict__ out) {
    __shared__ float s_in[4608];
    const int b = blockIdx.x, tid = threadIdx.x;
    const float* ip = in + (size_t)b * 4608;
    for (int t = tid; t < 4608; t += 256) s_in[t] = ip[t];
    __syncthreads();
    const int cg = tid >> 4, pb = tid & 15;
    const int py = (pb >> 2) * 2, px = (pb & 3) * 2;
    float acc[4][2][2] = {};
    for (int ci = 0; ci < 32; ci++) {
        float win[6][6];
#pragma unroll
        for (int r = 0; r < 6; r++) {
            const float2* rp = (const float2*)(s_in + ci * 144 + (py + r) * 12 + px);
            float2 v0 = rp[0], v1 = rp[1], v2 = rp[2];
            win[r][0] = v0.x; win[r][1] = v0.y; win[r][2] = v1.x;
            win[r][3] = v1.y; win[r][4] = v2.x; win[r][5] = v2.y;
        }
#pragma unroll
        for (int c4 = 0; c4 < 4; c4++) {
            const float* wr = w + ((cg * 4 + c4) * 32 + ci) * 25;
#pragma unroll
            for (int ky = 0; ky < 5; ky++)
#pragma unroll
                for (int kx = 0; kx < 5; kx++) {
                    float wv = wr[ky * 5 + kx];
                    acc[c4][0][0] += win[ky][kx] * wv;
                    acc[c4][0][1] += win[ky][kx + 1] * wv;
                    acc[c4][1][0] += win[ky + 1][kx] * wv;
                    acc[c4][1][1] += win[ky + 1][kx + 1] * wv;
                }
        }
    }
    float* op = out + (size_t)b * 4096;
#pragma unroll
    for (int c4 = 0; c4 < 4; c4++) {
        int co = cg * 4 + c4;
        float bb = bias[co];
#pragma unroll
        for (int dy = 0; dy < 2; dy++)
#pragma unroll
            for (int dx = 0; dx < 2; dx++)
                op[co * 64 + (py + dy) * 8 + px + dx] = acc[c4][dy][dx] + bb;
    }
}

// ---------------------------------------------------------------------------
// K4: conv4 + maxpool2 + flatten -> emb [B,256]. 256 threads: tid = co*4 + pp.
// ---------------------------------------------------------------------------
__global__ __launch_bounds__(256) void k_conv4(const float* __restrict__ in,
                                               const float* __restrict__ w,
                                               const float* __restrict__ bias,
                                               float* __restrict__ out_emb) {
    __shared__ float s_in[4096];
    const int b = blockIdx.x, tid = threadIdx.x;
    const float* ip = in + (size_t)b * 4096;
    for (int t = tid; t < 4096; t += 256) s_in[t] = ip[t];
    __syncthreads();
    const int co = tid >> 2, pp = tid & 3;
    const int ppy = pp >> 1, ppx = pp & 1;
    const int y0 = ppy * 2, x0 = ppx * 2;
    float acc[2][2] = {};
    for (int ci = 0; ci < 64; ci++) {
        float win[6][6];
#pragma unroll
        for (int r = 0; r < 6; r++) {
            const float2* rp = (const float2*)(s_in + ci * 64 + (y0 + r) * 8 + x0);
            float2 v0 = rp[0], v1 = rp[1], v2 = rp[2];
            win[r][0] = v0.x; win[r][1] = v0.y; win[r][2] = v1.x;
            win[r][3] = v1.y; win[r][4] = v2.x; win[r][5] = v2.y;
        }
        const float* wr = w + (co * 64 + ci) * 25;
#pragma unroll
        for (int ky = 0; ky < 5; ky++)
#pragma unroll
            for (int kx = 0; kx < 5; kx++) {
                float wv = wr[ky * 5 + kx];
                acc[0][0] += win[ky][kx] * wv;
                acc[0][1] += win[ky][kx + 1] * wv;
                acc[1][0] += win[ky + 1][kx] * wv;
                acc[1][1] += win[ky + 1][kx + 1] * wv;
            }
    }
    float mres = fmaxf(fmaxf(acc[0][0], acc[0][1]), fmaxf(acc[1][0], acc[1][1])) + bias[co];
    out_emb[(size_t)b * 256 + co * 4 + pp] = mres;
}

// ---------------------------------------------------------------------------
// K5: heads + DAMP recurrence (unchanged, verified round 1)
// ---------------------------------------------------------------------------
__global__ __launch_bounds__(256) void k_heads_path(
    const float* __restrict__ emb,
    const float* __restrict__ ep_w1, const float* __restrict__ ep_b1,
    const float* __restrict__ ep_w2, const float* __restrict__ ep_b2,
    const float* __restrict__ cn_w1, const float* __restrict__ cn_b1,
    const float* __restrict__ cn_w2, const float* __restrict__ cn_b2,
    float* __restrict__ out) {
    __shared__ float s_emb[256];
    __shared__ float s_hid[256];
    __shared__ float s_conn[120];
    __shared__ float s_old[120];
    __shared__ float s_rec[120];
    __shared__ float s_s[36];
    __shared__ float s_ep[36];
    const int b = blockIdx.x, tid = threadIdx.x;
    s_emb[tid] = emb[(size_t)b * 256 + tid];
    __syncthreads();

    {
        float h = cn_b1[tid];
        const float4* wr = (const float4*)(cn_w1 + (size_t)tid * 256);
        const float4* er = (const float4*)s_emb;
        for (int k = 0; k < 64; k++) {
            float4 wv = wr[k], ev = er[k];
            h += wv.x * ev.x + wv.y * ev.y + wv.z * ev.z + wv.w * ev.w;
        }
        s_hid[tid] = fmaxf(h, 0.f);
    }
    __syncthreads();

    if (tid < 120) {
        float a = cn_b2[tid];
        const float4* wr = (const float4*)(cn_w2 + (size_t)tid * 256);
        const float4* hr = (const float4*)s_hid;
        for (int k = 0; k < 64; k++) {
            float4 wv = wr[k], hv = hr[k];
            a += wv.x * hv.x + wv.y * hv.y + wv.z * hv.z + wv.w * hv.w;
        }
        float c = 1.f / (1.f + __expf(-a));
        s_conn[tid] = c;
        s_old[tid] = c;
        s_rec[tid] = c;
    }

    float h2 = ep_b1[tid];
    {
        const float4* wr = (const float4*)(ep_w1 + (size_t)tid * 256);
        const float4* er = (const float4*)s_emb;
        for (int k = 0; k < 64; k++) {
            float4 wv = wr[k], ev = er[k];
            h2 += wv.x * ev.x + wv.y * ev.y + wv.z * ev.z + wv.w * ev.w;
        }
    }
    __syncthreads();
    s_hid[tid] = fmaxf(h2, 0.f);
    __syncthreads();

    if (tid < 36) {
        float a = ep_b2[tid];
        const float4* wr = (const float4*)(ep_w2 + (size_t)tid * 256);
        const float4* hr = (const float4*)s_hid;
        for (int k = 0; k < 64; k++) {
            float4 wv = wr[k], hv = hr[k];
            a += wv.x * hv.x + wv.y * hv.y + wv.z * hv.z + wv.w * hv.w;
        }
        s_ep[tid] = 1.f / (1.f + __expf(-a));
    }
    __syncthreads();

    for (int it = 0; it < 36; it++) {
        if (tid < 36) {
            float sum = 0.f;
            int nn = ADJC.cnt[tid];
#pragma unroll
            for (int q = 0; q < 4; q++)
                sum += (q < nn) ? s_rec[ADJC.idx[tid][q]] : 0.f;
            s_s[tid] = sum;
        }
        __syncthreads();
        if (tid < 120) {
            float nv = fminf(s_s[ADJC.src[tid]], 1.f) * s_conn[tid];
            s_old[tid] = fminf(s_old[tid] + nv, 1.f);
            s_rec[tid] = nv;
        }
        __syncthreads();
    }

    if (tid == 0) out[b] = s_old[0] * s_ep[0] * s_ep[ADJC.dst[0]];
}

// ---------------------------------------------------------------------------
extern "C" void kernel_launch(void* const* d_in, const int* in_sizes, int n_in,
                              void* d_out, int out_size, void* d_ws, size_t ws_size,
                              hipStream_t stream) {
    const float* image = (const float*)d_in[0];
    const float* c1w = (const float*)d_in[1];
    const float* c1b = (const float*)d_in[2];
    const float* c2w = (const float*)d_in[3];
    const float* c2b = (const float*)d_in[4];
    const float* c3w = (const float*)d_in[5];
    const float* c3b = (const float*)d_in[6];
    const float* c4w = (const float*)d_in[7];
    const float* c4b = (const float*)d_in[8];
    const float* epw1 = (const float*)d_in[9];
    const float* epb1 = (const float*)d_in[10];
    const float* epw2 = (const float*)d_in[11];
    const float* epb2 = (const float*)d_in[12];
    const float* cnw1 = (const float*)d_in[13];
    const float* cnb1 = (const float*)d_in[14];
    const float* cnw2 = (const float*)d_in[15];
    const float* cnb2 = (const float*)d_in[16];

    const int B = in_sizes[0] / (32 * 32);  // 1024

    char* wsb = (char*)d_ws;
    unsigned short* conv1o = (unsigned short*)wsb;                 // B*25088 bf16
    float* pool2o = (float*)(wsb + (size_t)B * 25088 * 2);         // B*4608 f32
    float* conv3o = pool2o + (size_t)B * 4608;                     // B*4096 f32
    float* embo = conv3o + (size_t)B * 4096;                       // B*256 f32
    unsigned short* wprep = (unsigned short*)(embo + (size_t)B * 256);  // 25600 bf16

    k_prep<<<100, 256, 0, stream>>>(c2w, wprep);
    k_conv1<<<B, 256, 0, stream>>>(image, c1w, c1b, conv1o);
    k_conv2<<<B * 2, 128, 0, stream>>>(conv1o, wprep, c2b, pool2o);
    k_conv3<<<B, 256, 0, stream>>>(pool2o, c3w, c3b, conv3o);
    k_conv4<<<B, 256, 0, stream>>>(conv3o, c4w, c4b, embo);
    k_heads_path<<<B, 256, 0, stream>>>(embo, epw1, epb1, epw2, epb2,
                                        cnw1, cnb1, cnw2, cnb2, (float*)d_out);
}

// Round 3
// 315.067 us; speedup vs baseline: 3.3367x; 1.4471x over previous
//
#include <hip/hip_runtime.h>
#include <math.h>

typedef __attribute__((ext_vector_type(8))) short short8;
typedef __attribute__((ext_vector_type(4))) float float4v;

static __device__ __forceinline__ unsigned short f2bf(float f) {
    union { float f; unsigned u; } v; v.f = f;
    unsigned u = v.u;
    return (unsigned short)((u + 0x7fffu + ((u >> 16) & 1u)) >> 16);
}
static __device__ __forceinline__ float bf2f(unsigned short h) {
    union { unsigned u; float f; } v; v.u = ((unsigned)h) << 16;
    return v.f;
}

// ---------------------------------------------------------------------------
// Graph structure (compile-time), matching Python enumeration order.
// ---------------------------------------------------------------------------
struct AdjT {
    int src[120];
    int dst[120];
    int cnt[36];
    int idx[36][4];
};

constexpr AdjT build_adj() {
    AdjT a{};
    const int ddx[4] = {-1, 0, 0, 1};
    const int ddy[4] = {0, -1, 1, 0};
    int ne = 0;
    for (int i = 0; i < 6; i++)
        for (int j = 0; j < 6; j++)
            for (int d = 0; d < 4; d++) {
                int x = i + ddx[d], y = j + ddy[d];
                if (x >= 0 && x < 6 && y >= 0 && y < 6) {
                    a.src[ne] = j * 6 + i;
                    a.dst[ne] = y * 6 + x;
                    ne++;
                }
            }
    for (int n = 0; n < 36; n++) {
        a.cnt[n] = 0;
        for (int e = 0; e < 120; e++)
            if (a.dst[e] == n) a.idx[n][a.cnt[n]++] = e;
    }
    return a;
}

__device__ constexpr AdjT ADJC = build_adj();

// ---------------------------------------------------------------------------
// K0: weight prep — B-fragments (bf16) for conv2/conv3/conv4 MFMA.
//  wp2: [25 taps][2 nt][64 lane][8 j]   co=nt*16+(lane&15), ci=(lane>>4)*8+j
//  wp3: [25][4 nt][64][8]               co=nt*16+n,         ci=q*8+j
//  wp4: [25][2 ks][4 nt][64][8]         co=nt*16+n,         ci=ks*32+q*8+j
// grid 700*256 = 179200 = 25600 + 51200 + 102400 exactly.
// ---------------------------------------------------------------------------
__global__ __launch_bounds__(256) void k_prep(const float* __restrict__ w2,
                                              const float* __restrict__ w3,
                                              const float* __restrict__ w4,
                                              unsigned short* __restrict__ wp2,
                                              unsigned short* __restrict__ wp3,
                                              unsigned short* __restrict__ wp4) {
    int e = blockIdx.x * 256 + threadIdx.x;
    if (e < 25600) {
        int j = e & 7, lane = (e >> 3) & 63, ct = (e >> 9) & 1, t = e >> 10;
        int co = ct * 16 + (lane & 15), ci = (lane >> 4) * 8 + j;
        wp2[e] = f2bf(w2[co * 800 + ci * 25 + t]);
    } else if (e < 76800) {
        int e3 = e - 25600;
        int j = e3 & 7, lane = (e3 >> 3) & 63, nt = (e3 >> 9) & 3, t = e3 >> 11;
        int co = nt * 16 + (lane & 15), ci = (lane >> 4) * 8 + j;
        wp3[e3] = f2bf(w3[(co * 32 + ci) * 25 + t]);
    } else {
        int e4 = e - 76800;
        int j = e4 & 7, lane = (e4 >> 3) & 63, nt = (e4 >> 9) & 3;
        int ks = (e4 >> 11) & 1, t = e4 >> 12;
        int co = nt * 16 + (lane & 15), ci = ks * 32 + (lane >> 4) * 8 + j;
        wp4[e4] = f2bf(w4[(co * 64 + ci) * 25 + t]);
    }
}

// ---------------------------------------------------------------------------
// K1: conv1 [B,1,32,32] -> channel-last bf16 [B, 28*28 pos, 32 ci]
// ---------------------------------------------------------------------------
__global__ __launch_bounds__(256) void k_conv1(const float* __restrict__ img,
                                               const float* __restrict__ w,
                                               const float* __restrict__ bias,
                                               unsigned short* __restrict__ out) {
    __shared__ float s_img[1024];
    __shared__ float s_w[800];
    __shared__ float s_b[32];
    const int b = blockIdx.x, tid = threadIdx.x;
    const float* ip = img + (size_t)b * 1024;
    for (int t = tid; t < 1024; t += 256) s_img[t] = ip[t];
    for (int t = tid; t < 800; t += 256) s_w[t] = w[t];
    if (tid < 32) s_b[tid] = bias[tid];
    __syncthreads();
    unsigned short* op = out + (size_t)b * 25088;
    for (int idx = tid; idx < 25088; idx += 256) {
        int c = idx & 31;
        int pos = idx >> 5;
        int y = pos / 28;
        int x = pos - y * 28;
        float acc = s_b[c];
        const float* wr = s_w + c * 25;
#pragma unroll
        for (int ky = 0; ky < 5; ky++)
#pragma unroll
            for (int kx = 0; kx < 5; kx++)
                acc += s_img[(y + ky) * 32 + x + kx] * wr[ky * 5 + kx];
        op[idx] = f2bf(acc);
    }
}

// ---------------------------------------------------------------------------
// K2: conv2 + maxpool2 via MFMA tap-GEMM (verified R2).
// Output now channel-last bf16 [B][144 pos][32 co] for conv34's A-frags.
// ---------------------------------------------------------------------------
__global__ __launch_bounds__(128) void k_conv2(const unsigned short* __restrict__ in,
                                               const unsigned short* __restrict__ wprep,
                                               const float* __restrict__ bias,
                                               unsigned short* __restrict__ out) {
    __shared__ unsigned short s_in[448 * 32];
    __shared__ unsigned short s_stage[288 * 32];
    const int blk = blockIdx.x;
    const int b = blk >> 1, half = blk & 1;
    const int tid = threadIdx.x;
    const int lane = tid & 63, wave = tid >> 6;
    const int m = lane & 15, quad = lane >> 4;

    {
        const short8* g8 = (const short8*)(in + (size_t)b * 25088 + half * 12 * 28 * 32);
        short8* s8 = (short8*)s_in;
        for (int i = tid; i < 1792; i += 128) s8[i] = g8[i];
    }

    int a_idx[9];
#pragma unroll
    for (int mt = 0; mt < 9; mt++) {
        int p = wave * 144 + mt * 16 + m;
        int yl = p / 24;
        int x = p - yl * 24;
        a_idx[mt] = (yl * 28 + x) * 32 + quad * 8;
    }

    float4v acc[9][2];
#pragma unroll
    for (int mt = 0; mt < 9; mt++) {
        acc[mt][0] = (float4v){0.f, 0.f, 0.f, 0.f};
        acc[mt][1] = (float4v){0.f, 0.f, 0.f, 0.f};
    }

    const short8* wp = (const short8*)wprep;
    short8 bw0 = wp[lane];
    short8 bw1 = wp[64 + lane];

    __syncthreads();

    for (int t = 0; t < 25; t++) {
        short8 nb0, nb1;
        if (t < 24) {
            nb0 = wp[(t + 1) * 128 + lane];
            nb1 = wp[(t + 1) * 128 + 64 + lane];
        }
        const int ky = t / 5, kx = t - ky * 5;
        const int toff = (ky * 28 + kx) * 32;
#pragma unroll
        for (int mt = 0; mt < 9; mt++) {
            short8 av = *(const short8*)(s_in + a_idx[mt] + toff);
            acc[mt][0] = __builtin_amdgcn_mfma_f32_16x16x32_bf16(av, bw0, acc[mt][0], 0, 0, 0);
            acc[mt][1] = __builtin_amdgcn_mfma_f32_16x16x32_bf16(av, bw1, acc[mt][1], 0, 0, 0);
        }
        if (t < 24) { bw0 = nb0; bw1 = nb1; }
    }

    const int n = lane & 15;
#pragma unroll
    for (int mt = 0; mt < 9; mt++) {
        int pbase = wave * 144 + mt * 16 + quad * 4;
#pragma unroll
        for (int r = 0; r < 4; r++) {
            s_stage[(pbase + r) * 32 + n] = f2bf(acc[mt][0][r]);
            s_stage[(pbase + r) * 32 + 16 + n] = f2bf(acc[mt][1][r]);
        }
    }
    __syncthreads();

    // pool 2x2 + bias -> channel-last bf16 [144][32]
    unsigned short* op = out + (size_t)b * 4608;
    for (int i = tid; i < 2304; i += 128) {
        int co = i & 31;
        int pos = i >> 5;
        int prl = pos / 12;
        int px = pos - prl * 12;
        int base = ((prl * 2) * 24 + px * 2) * 32 + co;
        float v0 = bf2f(s_stage[base]);
        float v1 = bf2f(s_stage[base + 32]);
        float v2 = bf2f(s_stage[base + 24 * 32]);
        float v3 = bf2f(s_stage[base + 25 * 32]);
        float mx = fmaxf(fmaxf(v0, v1), fmaxf(v2, v3));
        op[((half * 6 + prl) * 12 + px) * 32 + co] = f2bf(mx + bias[co]);
    }
}

// ---------------------------------------------------------------------------
// K34: fused conv3 + conv4 + pool + flatten via MFMA tap-GEMM.
// Block = 1 wave = 1 image.
//  Phase A (conv3): in [144][32] bf16 (LDS) -> out 64 pos x 64 co,
//    4 Mtiles x 4 Ntiles x 25 taps = 400 MFMAs; staged to LDS bf16 with
//    row stride 72 ushorts (pad +8: phase-B banks rotate, unpadded = 16-way).
//  Phase B (conv4): 25 taps x 2 Ksteps x 4 Ntiles = 200 MFMAs ->
//    [16 pos][64 co] fp32 in LDS -> pool 2x2 + bias -> emb[b][co*4+pp] fp32.
// ---------------------------------------------------------------------------
__global__ __launch_bounds__(64) void k_conv34(const unsigned short* __restrict__ p2,
                                               const unsigned short* __restrict__ wp3,
                                               const float* __restrict__ b3,
                                               const unsigned short* __restrict__ wp4,
                                               const float* __restrict__ b4,
                                               float* __restrict__ emb) {
    __shared__ unsigned short s_in[4608];  // [144][32]
    __shared__ unsigned short s_c3[4608];  // [64][72] padded
    __shared__ float s_c4[1024];           // [16][64]
    const int b = blockIdx.x, tid = threadIdx.x;
    const int m = tid & 15, q = tid >> 4;

    {
        const short8* g8 = (const short8*)(p2 + (size_t)b * 4608);
        short8* s8 = (short8*)s_in;
        for (int i = tid; i < 576; i += 64) s8[i] = g8[i];
    }

    // ---- phase A: conv3 ----
    int a_base[4];
#pragma unroll
    for (int mt = 0; mt < 4; mt++) {
        int p = mt * 16 + m;
        int y = p >> 3, x = p & 7;
        a_base[mt] = (y * 12 + x) * 32 + q * 8;
    }

    float4v acc3[4][4];
#pragma unroll
    for (int mt = 0; mt < 4; mt++)
#pragma unroll
        for (int nt = 0; nt < 4; nt++) acc3[mt][nt] = (float4v){0.f, 0.f, 0.f, 0.f};

    const short8* wp = (const short8*)wp3;  // [25][4][64]
    short8 bw[4];
#pragma unroll
    for (int nt = 0; nt < 4; nt++) bw[nt] = wp[nt * 64 + tid];

    __syncthreads();

    for (int t = 0; t < 25; t++) {
        short8 nb[4];
        if (t < 24) {
#pragma unroll
            for (int nt = 0; nt < 4; nt++) nb[nt] = wp[((t + 1) * 4 + nt) * 64 + tid];
        }
        const int ky = t / 5, kx = t - ky * 5;
        const int toff = (ky * 12 + kx) * 32;
#pragma unroll
        for (int mt = 0; mt < 4; mt++) {
            short8 av = *(const short8*)(s_in + a_base[mt] + toff);
#pragma unroll
            for (int nt = 0; nt < 4; nt++)
                acc3[mt][nt] = __builtin_amdgcn_mfma_f32_16x16x32_bf16(av, bw[nt], acc3[mt][nt], 0, 0, 0);
        }
        if (t < 24) {
#pragma unroll
            for (int nt = 0; nt < 4; nt++) bw[nt] = nb[nt];
        }
    }

    // stage conv3 out (+bias) to LDS bf16, row stride 72
    {
        float bb[4];
#pragma unroll
        for (int nt = 0; nt < 4; nt++) bb[nt] = b3[nt * 16 + m];
#pragma unroll
        for (int mt = 0; mt < 4; mt++)
#pragma unroll
            for (int nt = 0; nt < 4; nt++)
#pragma unroll
                for (int r = 0; r < 4; r++)
                    s_c3[(mt * 16 + q * 4 + r) * 72 + nt * 16 + m] =
                        f2bf(acc3[mt][nt][r] + bb[nt]);
    }
    __syncthreads();

    // ---- phase B: conv4 ----
    const int a4_base = ((m >> 2) * 8 + (m & 3)) * 72 + q * 8;
    float4v acc4[4];
#pragma unroll
    for (int nt = 0; nt < 4; nt++) acc4[nt] = (float4v){0.f, 0.f, 0.f, 0.f};

    const short8* wq = (const short8*)wp4;  // [25][2][4][64]
    short8 cw[8];
#pragma unroll
    for (int i = 0; i < 8; i++) cw[i] = wq[i * 64 + tid];

    for (int t = 0; t < 25; t++) {
        short8 nb[8];
        if (t < 24) {
#pragma unroll
            for (int i = 0; i < 8; i++) nb[i] = wq[((t + 1) * 8 + i) * 64 + tid];
        }
        const int ky = t / 5, kx = t - ky * 5;
        const int toff = (ky * 8 + kx) * 72;
#pragma unroll
        for (int ks = 0; ks < 2; ks++) {
            short8 av = *(const short8*)(s_c3 + a4_base + toff + ks * 32);
#pragma unroll
            for (int nt = 0; nt < 4; nt++)
                acc4[nt] = __builtin_amdgcn_mfma_f32_16x16x32_bf16(av, cw[ks * 4 + nt], acc4[nt], 0, 0, 0);
        }
        if (t < 24) {
#pragma unroll
            for (int i = 0; i < 8; i++) cw[i] = nb[i];
        }
    }

    // conv4 out -> LDS fp32 [16 pos][64 co]
#pragma unroll
    for (int nt = 0; nt < 4; nt++)
#pragma unroll
        for (int r = 0; r < 4; r++)
            s_c4[(q * 4 + r) * 64 + nt * 16 + m] = acc4[nt][r];
    __syncthreads();

    // pool 2x2 + bias + flatten (c*4 + h*2 + w); lane = co
    {
        float bb = b4[tid];
        float4 res;
        float* rp = (float*)&res;
#pragma unroll
        for (int pp = 0; pp < 4; pp++) {
            int y0 = (pp >> 1) * 2, x0 = (pp & 1) * 2;
            float v0 = s_c4[(y0 * 4 + x0) * 64 + tid];
            float v1 = s_c4[(y0 * 4 + x0 + 1) * 64 + tid];
            float v2 = s_c4[((y0 + 1) * 4 + x0) * 64 + tid];
            float v3 = s_c4[((y0 + 1) * 4 + x0 + 1) * 64 + tid];
            rp[pp] = fmaxf(fmaxf(v0, v1), fmaxf(v2, v3)) + bb;
        }
        ((float4*)(emb + (size_t)b * 256))[tid] = res;
    }
}

// ---------------------------------------------------------------------------
// K5: heads + DAMP recurrence (unchanged, verified R1/R2)
// ---------------------------------------------------------------------------
__global__ __launch_bounds__(256) void k_heads_path(
    const float* __restrict__ emb,
    const float* __restrict__ ep_w1, const float* __restrict__ ep_b1,
    const float* __restrict__ ep_w2, const float* __restrict__ ep_b2,
    const float* __restrict__ cn_w1, const float* __restrict__ cn_b1,
    const float* __restrict__ cn_w2, const float* __restrict__ cn_b2,
    float* __restrict__ out) {
    __shared__ float s_emb[256];
    __shared__ float s_hid[256];
    __shared__ float s_conn[120];
    __shared__ float s_old[120];
    __shared__ float s_rec[120];
    __shared__ float s_s[36];
    __shared__ float s_ep[36];
    const int b = blockIdx.x, tid = threadIdx.x;
    s_emb[tid] = emb[(size_t)b * 256 + tid];
    __syncthreads();

    {
        float h = cn_b1[tid];
        const float4* wr = (const float4*)(cn_w1 + (size_t)tid * 256);
        const float4* er = (const float4*)s_emb;
        for (int k = 0; k < 64; k++) {
            float4 wv = wr[k], ev = er[k];
            h += wv.x * ev.x + wv.y * ev.y + wv.z * ev.z + wv.w * ev.w;
        }
        s_hid[tid] = fmaxf(h, 0.f);
    }
    __syncthreads();

    if (tid < 120) {
        float a = cn_b2[tid];
        const float4* wr = (const float4*)(cn_w2 + (size_t)tid * 256);
        const float4* hr = (const float4*)s_hid;
        for (int k = 0; k < 64; k++) {
            float4 wv = wr[k], hv = hr[k];
            a += wv.x * hv.x + wv.y * hv.y + wv.z * hv.z + wv.w * hv.w;
        }
        float c = 1.f / (1.f + __expf(-a));
        s_conn[tid] = c;
        s_old[tid] = c;
        s_rec[tid] = c;
    }

    float h2 = ep_b1[tid];
    {
        const float4* wr = (const float4*)(ep_w1 + (size_t)tid * 256);
        const float4* er = (const float4*)s_emb;
        for (int k = 0; k < 64; k++) {
            float4 wv = wr[k], ev = er[k];
            h2 += wv.x * ev.x + wv.y * ev.y + wv.z * ev.z + wv.w * ev.w;
        }
    }
    __syncthreads();
    s_hid[tid] = fmaxf(h2, 0.f);
    __syncthreads();

    if (tid < 36) {
        float a = ep_b2[tid];
        const float4* wr = (const float4*)(ep_w2 + (size_t)tid * 256);
        const float4* hr = (const float4*)s_hid;
        for (int k = 0; k < 64; k++) {
            float4 wv = wr[k], hv = hr[k];
            a += wv.x * hv.x + wv.y * hv.y + wv.z * hv.z + wv.w * hv.w;
        }
        s_ep[tid] = 1.f / (1.f + __expf(-a));
    }
    __syncthreads();

    for (int it = 0; it < 36; it++) {
        if (tid < 36) {
            float sum = 0.f;
            int nn = ADJC.cnt[tid];
#pragma unroll
            for (int qq = 0; qq < 4; qq++)
                sum += (qq < nn) ? s_rec[ADJC.idx[tid][qq]] : 0.f;
            s_s[tid] = sum;
        }
        __syncthreads();
        if (tid < 120) {
            float nv = fminf(s_s[ADJC.src[tid]], 1.f) * s_conn[tid];
            s_old[tid] = fminf(s_old[tid] + nv, 1.f);
            s_rec[tid] = nv;
        }
        __syncthreads();
    }

    if (tid == 0) out[b] = s_old[0] * s_ep[0] * s_ep[ADJC.dst[0]];
}

// ---------------------------------------------------------------------------
extern "C" void kernel_launch(void* const* d_in, const int* in_sizes, int n_in,
                              void* d_out, int out_size, void* d_ws, size_t ws_size,
                              hipStream_t stream) {
    const float* image = (const float*)d_in[0];
    const float* c1w = (const float*)d_in[1];
    const float* c1b = (const float*)d_in[2];
    const float* c2w = (const float*)d_in[3];
    const float* c2b = (const float*)d_in[4];
    const float* c3w = (const float*)d_in[5];
    const float* c3b = (const float*)d_in[6];
    const float* c4w = (const float*)d_in[7];
    const float* c4b = (const float*)d_in[8];
    const float* epw1 = (const float*)d_in[9];
    const float* epb1 = (const float*)d_in[10];
    const float* epw2 = (const float*)d_in[11];
    const float* epb2 = (const float*)d_in[12];
    const float* cnw1 = (const float*)d_in[13];
    const float* cnb1 = (const float*)d_in[14];
    const float* cnw2 = (const float*)d_in[15];
    const float* cnb2 = (const float*)d_in[16];

    const int B = in_sizes[0] / (32 * 32);  // 1024

    char* wsb = (char*)d_ws;
    unsigned short* conv1o = (unsigned short*)wsb;            // B*25088 bf16
    unsigned short* p2 = conv1o + (size_t)B * 25088;          // B*4608 bf16
    float* embo = (float*)(p2 + (size_t)B * 4608);            // B*256 f32
    unsigned short* wp2 = (unsigned short*)(embo + (size_t)B * 256);  // 25600
    unsigned short* wp3 = wp2 + 25600;                        // 51200
    unsigned short* wp4 = wp3 + 51200;                        // 102400

    k_prep<<<700, 256, 0, stream>>>(c2w, c3w, c4w, wp2, wp3, wp4);
    k_conv1<<<B, 256, 0, stream>>>(image, c1w, c1b, conv1o);
    k_conv2<<<B * 2, 128, 0, stream>>>(conv1o, wp2, c2b, p2);
    k_conv34<<<B, 64, 0, stream>>>(p2, wp3, c3b, wp4, c4b, embo);
    k_heads_path<<<B, 256, 0, stream>>>(embo, epw1, epb1, epw2, epb2,
                                        cnw1, cnb1, cnw2, cnb2, (float*)d_out);
}

// Round 4
// 253.301 us; speedup vs baseline: 4.1503x; 1.2438x over previous
//
#include <hip/hip_runtime.h>
#include <math.h>

typedef __attribute__((ext_vector_type(8))) short short8;
typedef __attribute__((ext_vector_type(4))) float float4v;
typedef __attribute__((ext_vector_type(4))) unsigned short ushort4v;

static __device__ __forceinline__ unsigned short f2bf(float f) {
    union { float f; unsigned u; } v; v.f = f;
    unsigned u = v.u;
    return (unsigned short)((u + 0x7fffu + ((u >> 16) & 1u)) >> 16);
}
static __device__ __forceinline__ float bf2f(unsigned short h) {
    union { unsigned u; float f; } v; v.u = ((unsigned)h) << 16;
    return v.f;
}

// ---------------------------------------------------------------------------
// Graph structure (compile-time), matching Python enumeration order.
// Edges are generated grouped by src node (contiguous runs), so out-edge
// lists are [ostart[n], ostart[n]+ocnt[n]).
// ---------------------------------------------------------------------------
struct AdjT {
    int src[120];
    int dst[120];
    int cnt[36];
    int idx[36][4];    // incoming edges per node
    int ostart[36];    // outgoing edge run start
    int ocnt[36];      // outgoing edge run length
};

constexpr AdjT build_adj() {
    AdjT a{};
    const int ddx[4] = {-1, 0, 0, 1};
    const int ddy[4] = {0, -1, 1, 0};
    int ne = 0;
    for (int i = 0; i < 6; i++)
        for (int j = 0; j < 6; j++)
            for (int d = 0; d < 4; d++) {
                int x = i + ddx[d], y = j + ddy[d];
                if (x >= 0 && x < 6 && y >= 0 && y < 6) {
                    a.src[ne] = j * 6 + i;
                    a.dst[ne] = y * 6 + x;
                    ne++;
                }
            }
    for (int n = 0; n < 36; n++) {
        a.cnt[n] = 0;
        for (int e = 0; e < 120; e++)
            if (a.dst[e] == n) a.idx[n][a.cnt[n]++] = e;
    }
    for (int n = 0; n < 36; n++) { a.ostart[n] = 0; a.ocnt[n] = 0; }
    for (int e = 0; e < 120; e++) {
        a.ocnt[a.src[e]]++;
        if (e == 0 || a.src[e] != a.src[e - 1]) a.ostart[a.src[e]] = e;
    }
    return a;
}

__device__ constexpr AdjT ADJC = build_adj();
// 16 thread-groups x {3,3,3,3,2,2,2,2,2,2,2,2,2,2,2,2} nodes = 36
__device__ constexpr int G16_START[17] =
    {0, 3, 6, 9, 12, 14, 16, 18, 20, 22, 24, 26, 28, 30, 32, 34, 36};

// ---------------------------------------------------------------------------
// K0: weight prep — B-fragments (bf16) for conv2/conv3/conv4 MFMA.
// ---------------------------------------------------------------------------
__global__ __launch_bounds__(256) void k_prep(const float* __restrict__ w2,
                                              const float* __restrict__ w3,
                                              const float* __restrict__ w4,
                                              unsigned short* __restrict__ wp2,
                                              unsigned short* __restrict__ wp3,
                                              unsigned short* __restrict__ wp4) {
    int e = blockIdx.x * 256 + threadIdx.x;
    if (e < 25600) {
        int j = e & 7, lane = (e >> 3) & 63, ct = (e >> 9) & 1, t = e >> 10;
        int co = ct * 16 + (lane & 15), ci = (lane >> 4) * 8 + j;
        wp2[e] = f2bf(w2[co * 800 + ci * 25 + t]);
    } else if (e < 76800) {
        int e3 = e - 25600;
        int j = e3 & 7, lane = (e3 >> 3) & 63, nt = (e3 >> 9) & 3, t = e3 >> 11;
        int co = nt * 16 + (lane & 15), ci = (lane >> 4) * 8 + j;
        wp3[e3] = f2bf(w3[(co * 32 + ci) * 25 + t]);
    } else {
        int e4 = e - 76800;
        int j = e4 & 7, lane = (e4 >> 3) & 63, nt = (e4 >> 9) & 3;
        int ks = (e4 >> 11) & 1, t = e4 >> 12;
        int co = nt * 16 + (lane & 15), ci = ks * 32 + (lane >> 4) * 8 + j;
        wp4[e4] = f2bf(w4[(co * 64 + ci) * 25 + t]);
    }
}

// ---------------------------------------------------------------------------
// K0b: weight prep for heads MFMA.
//  wph1:  [8kt][32nt][64][8]  c=nt*16+m (0..511: cn_w1|ep_w1), k=kt*32+q*8+j
//  wpcn2: [8kt][8nt][64][8]   c=nt*16+m (<120 else 0), k as above
//  wpep2: [8kt][3nt][64][8]   c=nt*16+m (<36 else 0)
// grid 688*256 = 176128 = 131072 + 32768 + 12288 exactly.
// ---------------------------------------------------------------------------
__global__ __launch_bounds__(256) void k_prep2(const float* __restrict__ cnw1,
                                               const float* __restrict__ epw1,
                                               const float* __restrict__ cnw2,
                                               const float* __restrict__ epw2,
                                               unsigned short* __restrict__ wph1,
                                               unsigned short* __restrict__ wpcn2,
                                               unsigned short* __restrict__ wpep2) {
    int e = blockIdx.x * 256 + threadIdx.x;
    if (e < 131072) {
        int j = e & 7, lane = (e >> 3) & 63, nt = (e >> 9) & 31, kt = e >> 14;
        int c = nt * 16 + (lane & 15);
        int k = kt * 32 + ((lane >> 4) << 3) + j;
        float v = (c < 256) ? cnw1[c * 256 + k] : epw1[(c - 256) * 256 + k];
        wph1[e] = f2bf(v);
    } else if (e < 163840) {
        int e2 = e - 131072;
        int j = e2 & 7, lane = (e2 >> 3) & 63, nt = (e2 >> 9) & 7, kt = e2 >> 12;
        int c = nt * 16 + (lane & 15);
        int k = kt * 32 + ((lane >> 4) << 3) + j;
        wpcn2[e2] = f2bf(c < 120 ? cnw2[c * 256 + k] : 0.f);
    } else {
        int e3 = e - 163840;
        int j = e3 & 7, lane = (e3 >> 3) & 63, idx = e3 >> 9;
        int kt = idx / 3, nt = idx - kt * 3;
        int c = nt * 16 + (lane & 15);
        int k = kt * 32 + ((lane >> 4) << 3) + j;
        wpep2[e3] = f2bf(c < 36 ? epw2[c * 256 + k] : 0.f);
    }
}

// ---------------------------------------------------------------------------
// K1: conv1 [B,1,32,32] -> channel-last bf16 [B, 28*28 pos, 32 ci]
// ---------------------------------------------------------------------------
__global__ __launch_bounds__(256) void k_conv1(const float* __restrict__ img,
                                               const float* __restrict__ w,
                                               const float* __restrict__ bias,
                                               unsigned short* __restrict__ out) {
    __shared__ float s_img[1024];
    __shared__ float s_w[800];
    __shared__ float s_b[32];
    const int b = blockIdx.x, tid = threadIdx.x;
    const float* ip = img + (size_t)b * 1024;
    for (int t = tid; t < 1024; t += 256) s_img[t] = ip[t];
    for (int t = tid; t < 800; t += 256) s_w[t] = w[t];
    if (tid < 32) s_b[tid] = bias[tid];
    __syncthreads();
    unsigned short* op = out + (size_t)b * 25088;
    for (int idx = tid; idx < 25088; idx += 256) {
        int c = idx & 31;
        int pos = idx >> 5;
        int y = pos / 28;
        int x = pos - y * 28;
        float acc = s_b[c];
        const float* wr = s_w + c * 25;
#pragma unroll
        for (int ky = 0; ky < 5; ky++)
#pragma unroll
            for (int kx = 0; kx < 5; kx++)
                acc += s_img[(y + ky) * 32 + x + kx] * wr[ky * 5 + kx];
        op[idx] = f2bf(acc);
    }
}

// ---------------------------------------------------------------------------
// K2: conv2 + maxpool2 via MFMA tap-GEMM (verified R2/R3).
// ---------------------------------------------------------------------------
__global__ __launch_bounds__(128) void k_conv2(const unsigned short* __restrict__ in,
                                               const unsigned short* __restrict__ wprep,
                                               const float* __restrict__ bias,
                                               unsigned short* __restrict__ out) {
    __shared__ unsigned short s_in[448 * 32];
    __shared__ unsigned short s_stage[288 * 32];
    const int blk = blockIdx.x;
    const int b = blk >> 1, half = blk & 1;
    const int tid = threadIdx.x;
    const int lane = tid & 63, wave = tid >> 6;
    const int m = lane & 15, quad = lane >> 4;

    {
        const short8* g8 = (const short8*)(in + (size_t)b * 25088 + half * 12 * 28 * 32);
        short8* s8 = (short8*)s_in;
        for (int i = tid; i < 1792; i += 128) s8[i] = g8[i];
    }

    int a_idx[9];
#pragma unroll
    for (int mt = 0; mt < 9; mt++) {
        int p = wave * 144 + mt * 16 + m;
        int yl = p / 24;
        int x = p - yl * 24;
        a_idx[mt] = (yl * 28 + x) * 32 + quad * 8;
    }

    float4v acc[9][2];
#pragma unroll
    for (int mt = 0; mt < 9; mt++) {
        acc[mt][0] = (float4v){0.f, 0.f, 0.f, 0.f};
        acc[mt][1] = (float4v){0.f, 0.f, 0.f, 0.f};
    }

    const short8* wp = (const short8*)wprep;
    short8 bw0 = wp[lane];
    short8 bw1 = wp[64 + lane];

    __syncthreads();

    for (int t = 0; t < 25; t++) {
        short8 nb0, nb1;
        if (t < 24) {
            nb0 = wp[(t + 1) * 128 + lane];
            nb1 = wp[(t + 1) * 128 + 64 + lane];
        }
        const int ky = t / 5, kx = t - ky * 5;
        const int toff = (ky * 28 + kx) * 32;
#pragma unroll
        for (int mt = 0; mt < 9; mt++) {
            short8 av = *(const short8*)(s_in + a_idx[mt] + toff);
            acc[mt][0] = __builtin_amdgcn_mfma_f32_16x16x32_bf16(av, bw0, acc[mt][0], 0, 0, 0);
            acc[mt][1] = __builtin_amdgcn_mfma_f32_16x16x32_bf16(av, bw1, acc[mt][1], 0, 0, 0);
        }
        if (t < 24) { bw0 = nb0; bw1 = nb1; }
    }

    const int n = lane & 15;
#pragma unroll
    for (int mt = 0; mt < 9; mt++) {
        int pbase = wave * 144 + mt * 16 + quad * 4;
#pragma unroll
        for (int r = 0; r < 4; r++) {
            s_stage[(pbase + r) * 32 + n] = f2bf(acc[mt][0][r]);
            s_stage[(pbase + r) * 32 + 16 + n] = f2bf(acc[mt][1][r]);
        }
    }
    __syncthreads();

    unsigned short* op = out + (size_t)b * 4608;
    for (int i = tid; i < 2304; i += 128) {
        int co = i & 31;
        int pos = i >> 5;
        int prl = pos / 12;
        int px = pos - prl * 12;
        int base = ((prl * 2) * 24 + px * 2) * 32 + co;
        float v0 = bf2f(s_stage[base]);
        float v1 = bf2f(s_stage[base + 32]);
        float v2 = bf2f(s_stage[base + 24 * 32]);
        float v3 = bf2f(s_stage[base + 25 * 32]);
        float mx = fmaxf(fmaxf(v0, v1), fmaxf(v2, v3));
        op[((half * 6 + prl) * 12 + px) * 32 + co] = f2bf(mx + bias[co]);
    }
}

// ---------------------------------------------------------------------------
// K34: fused conv3 + conv4 + pool + flatten via MFMA tap-GEMM (verified R3).
// Epilogue now writes emb as bf16 [B][256] (row-major = heads A-frag layout).
// ---------------------------------------------------------------------------
__global__ __launch_bounds__(64) void k_conv34(const unsigned short* __restrict__ p2,
                                               const unsigned short* __restrict__ wp3,
                                               const float* __restrict__ b3,
                                               const unsigned short* __restrict__ wp4,
                                               const float* __restrict__ b4,
                                               unsigned short* __restrict__ emb) {
    __shared__ unsigned short s_in[4608];
    __shared__ unsigned short s_c3[4608];
    __shared__ float s_c4[1024];
    const int b = blockIdx.x, tid = threadIdx.x;
    const int m = tid & 15, q = tid >> 4;

    {
        const short8* g8 = (const short8*)(p2 + (size_t)b * 4608);
        short8* s8 = (short8*)s_in;
        for (int i = tid; i < 576; i += 64) s8[i] = g8[i];
    }

    int a_base[4];
#pragma unroll
    for (int mt = 0; mt < 4; mt++) {
        int p = mt * 16 + m;
        int y = p >> 3, x = p & 7;
        a_base[mt] = (y * 12 + x) * 32 + q * 8;
    }

    float4v acc3[4][4];
#pragma unroll
    for (int mt = 0; mt < 4; mt++)
#pragma unroll
        for (int nt = 0; nt < 4; nt++) acc3[mt][nt] = (float4v){0.f, 0.f, 0.f, 0.f};

    const short8* wp = (const short8*)wp3;
    short8 bw[4];
#pragma unroll
    for (int nt = 0; nt < 4; nt++) bw[nt] = wp[nt * 64 + tid];

    __syncthreads();

    for (int t = 0; t < 25; t++) {
        short8 nb[4];
        if (t < 24) {
#pragma unroll
            for (int nt = 0; nt < 4; nt++) nb[nt] = wp[((t + 1) * 4 + nt) * 64 + tid];
        }
        const int ky = t / 5, kx = t - ky * 5;
        const int toff = (ky * 12 + kx) * 32;
#pragma unroll
        for (int mt = 0; mt < 4; mt++) {
            short8 av = *(const short8*)(s_in + a_base[mt] + toff);
#pragma unroll
            for (int nt = 0; nt < 4; nt++)
                acc3[mt][nt] = __builtin_amdgcn_mfma_f32_16x16x32_bf16(av, bw[nt], acc3[mt][nt], 0, 0, 0);
        }
        if (t < 24) {
#pragma unroll
            for (int nt = 0; nt < 4; nt++) bw[nt] = nb[nt];
        }
    }

    {
        float bb[4];
#pragma unroll
        for (int nt = 0; nt < 4; nt++) bb[nt] = b3[nt * 16 + m];
#pragma unroll
        for (int mt = 0; mt < 4; mt++)
#pragma unroll
            for (int nt = 0; nt < 4; nt++)
#pragma unroll
                for (int r = 0; r < 4; r++)
                    s_c3[(mt * 16 + q * 4 + r) * 72 + nt * 16 + m] =
                        f2bf(acc3[mt][nt][r] + bb[nt]);
    }
    __syncthreads();

    const int a4_base = ((m >> 2) * 8 + (m & 3)) * 72 + q * 8;
    float4v acc4[4];
#pragma unroll
    for (int nt = 0; nt < 4; nt++) acc4[nt] = (float4v){0.f, 0.f, 0.f, 0.f};

    const short8* wq = (const short8*)wp4;
    short8 cw[8];
#pragma unroll
    for (int i = 0; i < 8; i++) cw[i] = wq[i * 64 + tid];

    for (int t = 0; t < 25; t++) {
        short8 nb[8];
        if (t < 24) {
#pragma unroll
            for (int i = 0; i < 8; i++) nb[i] = wq[((t + 1) * 8 + i) * 64 + tid];
        }
        const int ky = t / 5, kx = t - ky * 5;
        const int toff = (ky * 8 + kx) * 72;
#pragma unroll
        for (int ks = 0; ks < 2; ks++) {
            short8 av = *(const short8*)(s_c3 + a4_base + toff + ks * 32);
#pragma unroll
            for (int nt = 0; nt < 4; nt++)
                acc4[nt] = __builtin_amdgcn_mfma_f32_16x16x32_bf16(av, cw[ks * 4 + nt], acc4[nt], 0, 0, 0);
        }
        if (t < 24) {
#pragma unroll
            for (int i = 0; i < 8; i++) cw[i] = nb[i];
        }
    }

#pragma unroll
    for (int nt = 0; nt < 4; nt++)
#pragma unroll
        for (int r = 0; r < 4; r++)
            s_c4[(q * 4 + r) * 64 + nt * 16 + m] = acc4[nt][r];
    __syncthreads();

    {
        float bb = b4[tid];
        ushort4v res;
#pragma unroll
        for (int pp = 0; pp < 4; pp++) {
            int y0 = (pp >> 1) * 2, x0 = (pp & 1) * 2;
            float v0 = s_c4[(y0 * 4 + x0) * 64 + tid];
            float v1 = s_c4[(y0 * 4 + x0 + 1) * 64 + tid];
            float v2 = s_c4[((y0 + 1) * 4 + x0) * 64 + tid];
            float v3 = s_c4[((y0 + 1) * 4 + x0 + 1) * 64 + tid];
            res[pp] = f2bf(fmaxf(fmaxf(v0, v1), fmaxf(v2, v3)) + bb);
        }
        *(ushort4v*)(emb + (size_t)b * 256 + tid * 4) = res;
    }
}

// ---------------------------------------------------------------------------
// K5: fused heads (MFMA) + DAMP recurrence. Block = 16 batch rows, 256 thr.
//  Phase 1: hid[16][512] = relu(emb @ [cn_w1;ep_w1]^T + b) via MFMA,
//           A-frags from global bf16 emb, B-frags prepped; -> LDS (stride 520).
//  Phase 2: logits: conn (8 N-tiles, pad 128) + ep (3 N-tiles, pad 48),
//           K=256 each (hid halves); sigmoid -> conn/rec0/ep in [edge][17]
//           LDS layout (stride-17 = conflict-free column writes).
//  Phase 3: 36-iter recurrence, node-centric, 1 barrier/iter, rec dbuf;
//           conn of owned out-edges in registers; only old[edge 0] tracked.
// ---------------------------------------------------------------------------
__global__ __launch_bounds__(256) void k_heads(
    const unsigned short* __restrict__ emb,
    const unsigned short* __restrict__ wph1,
    const float* __restrict__ cn_b1, const float* __restrict__ ep_b1,
    const unsigned short* __restrict__ wpcn2, const float* __restrict__ cn_b2,
    const unsigned short* __restrict__ wpep2, const float* __restrict__ ep_b2,
    float* __restrict__ out) {
    __shared__ unsigned short s_hid[16 * 520];
    __shared__ float s_conn[120 * 17];
    __shared__ float s_rec0[120 * 17];
    __shared__ float s_rec1[120 * 17];
    __shared__ float s_ep[36 * 17];
    const int tid = threadIdx.x;
    const int lane = tid & 63, wave = tid >> 6;
    const int m = lane & 15, q = lane >> 4;
    const int b0 = blockIdx.x * 16;

    // ---- phase 1: hidden layer ----
    float4v acc[8];
#pragma unroll
    for (int i = 0; i < 8; i++) acc[i] = (float4v){0.f, 0.f, 0.f, 0.f};
    const short8* wp1 = (const short8*)wph1;
    for (int kt = 0; kt < 8; kt++) {
        short8 av = *(const short8*)(emb + (size_t)(b0 + m) * 256 + kt * 32 + q * 8);
#pragma unroll
        for (int ntl = 0; ntl < 8; ntl++) {
            int nt = wave * 8 + ntl;
            short8 bv = wp1[(kt * 32 + nt) * 64 + lane];
            acc[ntl] = __builtin_amdgcn_mfma_f32_16x16x32_bf16(av, bv, acc[ntl], 0, 0, 0);
        }
    }
#pragma unroll
    for (int ntl = 0; ntl < 8; ntl++) {
        int c = (wave * 8 + ntl) * 16 + m;
        float bb = (c < 256) ? cn_b1[c] : ep_b1[c - 256];
#pragma unroll
        for (int r = 0; r < 4; r++)
            s_hid[(q * 4 + r) * 520 + c] = f2bf(fmaxf(acc[ntl][r] + bb, 0.f));
    }
    __syncthreads();

    // ---- phase 2: logits + sigmoid ----
    for (int job = wave; job < 11; job += 4) {
        const bool isconn = job < 8;
        const int koff = isconn ? 0 : 256;
        float4v a2 = (float4v){0.f, 0.f, 0.f, 0.f};
        for (int kt = 0; kt < 8; kt++) {
            short8 av = *(const short8*)(s_hid + m * 520 + koff + kt * 32 + q * 8);
            short8 bv = isconn
                ? ((const short8*)wpcn2)[(kt * 8 + job) * 64 + lane]
                : ((const short8*)wpep2)[(kt * 3 + (job - 8)) * 64 + lane];
            a2 = __builtin_amdgcn_mfma_f32_16x16x32_bf16(av, bv, a2, 0, 0, 0);
        }
        int c = (isconn ? job : (job - 8)) * 16 + m;
        float bb = isconn ? (c < 120 ? cn_b2[c] : 0.f) : (c < 36 ? ep_b2[c] : 0.f);
#pragma unroll
        for (int r = 0; r < 4; r++) {
            float v = 1.f / (1.f + __expf(-(a2[r] + bb)));
            int row = q * 4 + r;
            if (isconn) {
                if (c < 120) { s_conn[c * 17 + row] = v; s_rec0[c * 17 + row] = v; }
            } else {
                if (c < 36) s_ep[c * 17 + row] = v;
            }
        }
    }
    __syncthreads();

    // ---- phase 3: recurrence (row = tid>>4, group g = tid&15) ----
    const int row = tid >> 4, g = tid & 15;
    const int ns = G16_START[g];
    const int nodecnt = G16_START[g + 1] - ns;  // 2 or 3
    int ie[3][4], icnt[3], os[3], oc[3];
    float cr[3][4];
#pragma unroll
    for (int s = 0; s < 3; s++) {
        if (s < nodecnt) {
            int n = ns + s;
            icnt[s] = ADJC.cnt[n];
#pragma unroll
            for (int qx = 0; qx < 4; qx++) ie[s][qx] = ADJC.idx[n][qx];
            os[s] = ADJC.ostart[n];
            oc[s] = ADJC.ocnt[n];
#pragma unroll
            for (int oe = 0; oe < 4; oe++)
                cr[s][oe] = (oe < oc[s]) ? s_conn[(os[s] + oe) * 17 + row] : 0.f;
        } else {
            icnt[s] = 0; oc[s] = 0; os[s] = 0;
#pragma unroll
            for (int qx = 0; qx < 4; qx++) ie[s][qx] = 0;
#pragma unroll
            for (int oe = 0; oe < 4; oe++) cr[s][oe] = 0.f;
        }
    }
    float old0 = (g == 0) ? s_conn[0 * 17 + row] : 0.f;  // node 0 owns edge 0

    for (int it = 0; it < 36; it++) {
        const float* cur = (it & 1) ? s_rec1 : s_rec0;
        float* nxt = (it & 1) ? s_rec0 : s_rec1;
#pragma unroll
        for (int s = 0; s < 3; s++) {
            float sum = 0.f;
#pragma unroll
            for (int qx = 0; qx < 4; qx++)
                sum += (qx < icnt[s]) ? cur[ie[s][qx] * 17 + row] : 0.f;
            sum = fminf(sum, 1.f);
#pragma unroll
            for (int oe = 0; oe < 4; oe++) {
                if (oe < oc[s]) {
                    int e = os[s] + oe;
                    float nv = sum * cr[s][oe];
                    nxt[e * 17 + row] = nv;
                    if (g == 0 && s == 0 && oe == 0)  // edge 0
                        old0 = fminf(old0 + nv, 1.f);
                }
            }
        }
        __syncthreads();
    }

    if (g == 0)
        out[b0 + row] = old0 * s_ep[0 * 17 + row] * s_ep[6 * 17 + row];
}

// ---------------------------------------------------------------------------
extern "C" void kernel_launch(void* const* d_in, const int* in_sizes, int n_in,
                              void* d_out, int out_size, void* d_ws, size_t ws_size,
                              hipStream_t stream) {
    const float* image = (const float*)d_in[0];
    const float* c1w = (const float*)d_in[1];
    const float* c1b = (const float*)d_in[2];
    const float* c2w = (const float*)d_in[3];
    const float* c2b = (const float*)d_in[4];
    const float* c3w = (const float*)d_in[5];
    const float* c3b = (const float*)d_in[6];
    const float* c4w = (const float*)d_in[7];
    const float* c4b = (const float*)d_in[8];
    const float* epw1 = (const float*)d_in[9];
    const float* epb1 = (const float*)d_in[10];
    const float* epw2 = (const float*)d_in[11];
    const float* epb2 = (const float*)d_in[12];
    const float* cnw1 = (const float*)d_in[13];
    const float* cnb1 = (const float*)d_in[14];
    const float* cnw2 = (const float*)d_in[15];
    const float* cnb2 = (const float*)d_in[16];

    const int B = in_sizes[0] / (32 * 32);  // 1024

    unsigned short* ws = (unsigned short*)d_ws;
    unsigned short* conv1o = ws;                          // B*25088 bf16
    unsigned short* p2 = conv1o + (size_t)B * 25088;      // B*4608 bf16
    unsigned short* embo = p2 + (size_t)B * 4608;         // B*256 bf16
    unsigned short* wp2 = embo + (size_t)B * 256;         // 25600
    unsigned short* wp3 = wp2 + 25600;                    // 51200
    unsigned short* wp4 = wp3 + 51200;                    // 102400
    unsigned short* wph1 = wp4 + 102400;                  // 131072
    unsigned short* wpcn2 = wph1 + 131072;                // 32768
    unsigned short* wpep2 = wpcn2 + 32768;                // 12288

    k_prep<<<700, 256, 0, stream>>>(c2w, c3w, c4w, wp2, wp3, wp4);
    k_prep2<<<688, 256, 0, stream>>>(cnw1, epw1, cnw2, epw2, wph1, wpcn2, wpep2);
    k_conv1<<<B, 256, 0, stream>>>(image, c1w, c1b, conv1o);
    k_conv2<<<B * 2, 128, 0, stream>>>(conv1o, wp2, c2b, p2);
    k_conv34<<<B, 64, 0, stream>>>(p2, wp3, c3b, wp4, c4b, embo);
    k_heads<<<B / 16, 256, 0, stream>>>(embo, wph1, cnb1, epb1,
                                        wpcn2, cnb2, wpep2, epb2, (float*)d_out);
}